// Round 3
// baseline (558.687 us; speedup 1.0000x reference)
//
#include <hip/hip_runtime.h>
#include <hip/hip_bf16.h>

#define N_NODES   50000
#define N_PAD     50048                 // ceil64
#define N_EDGES   800000
#define N_REL     16
#define N_GRAPHS  64
#define DIM       128
#define FC_DIM    256
#define N_CLASSES 16

#define NBINS     (N_REL * N_PAD)       // 800768 = 782 * 1024 exactly
#define NBLK_SCAN 782
#define NTILES    782                   // N_PAD / 64
#define POOL_CH   64

// ---- ws layout (bytes, 256-aligned) ----
#define WS_HIST   0                     // 3203072 (NBINS*4)  } one contiguous
#define WS_HG     3203072               // 32768              } memset region
#define WS_CNT    3235840               // 256                }
#define MEMSET_SZ 3236096
#define WS_OFFS   3236096               // (NBINS+1)*4 pad -> 3203328
#define WS_CUR    6439424               // NBINS*4
#define WS_PART   9642496               // 4096
#define WS_SRCS   9646592               // 3200000
#define WS_X1     12846592              // 50048*128*2 = 12812288
#define WS_X2     25658880              // 12812288
#define WS_AGG2   38471168              // 50048*128*4 = 25624576
#define WS_WB     64095744              // 2 * 17*128*128*2 = 1114112 -> 65209856

typedef __attribute__((ext_vector_type(8))) short bf16x8;
typedef __attribute__((ext_vector_type(4))) float f32x4;

__device__ __forceinline__ void atomAddF(float* p, float v) {
#if defined(__gfx90a__) || defined(__gfx942__) || defined(__gfx950__)
    unsafeAtomicAdd(p, v);
#else
    atomicAdd(p, v);
#endif
}

__device__ __forceinline__ float bf2f(unsigned int u) {
    union { float f; unsigned int i; } x; x.i = u << 16; return x.f;
}
__device__ __forceinline__ unsigned short f2bf(float f) {
    union { float f; unsigned int u; } x; x.f = f;
    unsigned int r = x.u + 0x7fff + ((x.u >> 16) & 1);
    return (unsigned short)(r >> 16);
}

__device__ __forceinline__ void accum8(float* qa, uint4 u) {
    qa[0] += bf2f(u.x & 0xffff); qa[1] += bf2f(u.x >> 16);
    qa[2] += bf2f(u.y & 0xffff); qa[3] += bf2f(u.y >> 16);
    qa[4] += bf2f(u.z & 0xffff); qa[5] += bf2f(u.z >> 16);
    qa[6] += bf2f(u.w & 0xffff); qa[7] += bf2f(u.w >> 16);
}
__device__ __forceinline__ void accum32(float* qa, const uint4* p) {
    #pragma unroll
    for (int j = 0; j < 4; ++j) accum8(qa + j * 8, p[j]);
}
__device__ __forceinline__ void pack32(const float* qa, unsigned short* dst) {
    #pragma unroll
    for (int j = 0; j < 4; ++j) {
        uint4 w;
        w.x = ((unsigned int)f2bf(qa[j*8+1]) << 16) | f2bf(qa[j*8+0]);
        w.y = ((unsigned int)f2bf(qa[j*8+3]) << 16) | f2bf(qa[j*8+2]);
        w.z = ((unsigned int)f2bf(qa[j*8+5]) << 16) | f2bf(qa[j*8+4]);
        w.w = ((unsigned int)f2bf(qa[j*8+7]) << 16) | f2bf(qa[j*8+6]);
        ((uint4*)dst)[j] = w;
    }
}

// ---- x1 = bf16(h), zero-padded rows ----
__global__ void k_convX(const float* __restrict__ h, unsigned short* __restrict__ x1) {
    int i = blockIdx.x * blockDim.x + threadIdx.x;      // over N_PAD*DIM
    int v = i >> 7;
    x1[i] = (v < N_NODES) ? f2bf(h[i]) : (unsigned short)0;
}

// ---- Wb[l][r][n][k] = bf16(W_l[r][k][n]); r==16 -> Ws_l ---- (both layers)
__global__ void k_convW(const float* __restrict__ W1, const float* __restrict__ Ws1,
                        const float* __restrict__ W2, const float* __restrict__ Ws2,
                        unsigned short* __restrict__ Wb) {
    int id = blockIdx.x * blockDim.x + threadIdx.x;     // 2*17*16384
    int l = id / 278528, rem = id % 278528;
    int r = rem >> 14, rr = rem & 16383;
    int n = rr >> 7, k = rr & 127;
    const float* W  = l ? W2 : W1;
    const float* Ws = l ? Ws2 : Ws1;
    float v = (r < 16) ? W[r * 16384 + k * 128 + n] : Ws[k * 128 + n];
    Wb[id] = f2bf(v);
}

__global__ void k_histK(const int* __restrict__ dst, const int* __restrict__ rel,
                        int* __restrict__ hist) {
    int e = blockIdx.x * blockDim.x + threadIdx.x;
    if (e < N_EDGES) atomicAdd(&hist[rel[e] * N_PAD + dst[e]], 1);
}

__global__ void k_scanA(const int* __restrict__ hist, int* __restrict__ partials) {
    __shared__ int red[256];
    int b = blockIdx.x, t = threadIdx.x;
    int4 v = ((const int4*)(hist + b * 1024))[t];
    red[t] = v.x + v.y + v.z + v.w;
    __syncthreads();
    for (int o = 128; o > 0; o >>= 1) {
        if (t < o) red[t] += red[t + o];
        __syncthreads();
    }
    if (t == 0) partials[b] = red[0];
}

__global__ void k_scanB(int* __restrict__ partials, int* __restrict__ offs_tail) {
    __shared__ int s1[256], s2[256];
    int t = threadIdx.x;
    int v[4]; int sum = 0;
    #pragma unroll
    for (int i = 0; i < 4; ++i) {
        int j = t * 4 + i;
        v[i] = (j < NBLK_SCAN) ? partials[j] : 0;
        sum += v[i];
    }
    s1[t] = sum; __syncthreads();
    int* cur = s1; int* nxt = s2;
    for (int o = 1; o < 256; o <<= 1) {
        nxt[t] = cur[t] + ((t >= o) ? cur[t - o] : 0);
        __syncthreads();
        int* tmp = cur; cur = nxt; nxt = tmp;
    }
    int run = cur[t] - sum;
    #pragma unroll
    for (int i = 0; i < 4; ++i) {
        int j = t * 4 + i;
        if (j < NBLK_SCAN) partials[j] = run;
        run += v[i];
    }
    if (t == 255) offs_tail[0] = cur[255];
}

__global__ void k_scanC(const int* __restrict__ hist, const int* __restrict__ partials,
                        int* __restrict__ offs, int* __restrict__ curp) {
    __shared__ int s1[256], s2[256];
    int b = blockIdx.x, t = threadIdx.x;
    int4 v = ((const int4*)(hist + b * 1024))[t];
    int sum = v.x + v.y + v.z + v.w;
    s1[t] = sum; __syncthreads();
    int* cur = s1; int* nxt = s2;
    for (int o = 1; o < 256; o <<= 1) {
        nxt[t] = cur[t] + ((t >= o) ? cur[t - o] : 0);
        __syncthreads();
        int* tmp = cur; cur = nxt; nxt = tmp;
    }
    int base = partials[b] + cur[t] - sum;
    int4 w;
    w.x = base;
    w.y = base + v.x;
    w.z = w.y + v.y;
    w.w = w.z + v.z;
    ((int4*)(offs + b * 1024))[t] = w;
    ((int4*)(curp + b * 1024))[t] = w;
}

__global__ void k_scatterK(const int* __restrict__ src, const int* __restrict__ dst,
                           const int* __restrict__ rel, int* __restrict__ cur,
                           int* __restrict__ srcs) {
    int e = blockIdx.x * blockDim.x + threadIdx.x;
    if (e < N_EDGES) {
        int key = rel[e] * N_PAD + dst[e];
        int pos = atomicAdd(&cur[key], 1);
        srcs[pos] = src[e];
    }
}

// ---- fused RGCN layer, pipelined ----
// Block: 64 dsts. Wave w: 64 rows x cols [w*32, w*32+32). B in regs from global.
// Double-buffered Q tile; gathers for rel r+1 prefetched before rel r's MFMA.
#define QT_STRIDE 136
#define QSZ       (64 * QT_STRIDE)
__global__ __launch_bounds__(256) void k_layer(
    const unsigned short* __restrict__ x, const unsigned short* __restrict__ Wb,
    const int* __restrict__ offs, const int* __restrict__ srcs,
    const float* __restrict__ bias,
    unsigned short* __restrict__ out_bf16, float* __restrict__ out_f32)
{
    __shared__ unsigned short Qt[2 * QSZ];

    int tid = threadIdx.x;
    int v0  = blockIdx.x * 64;
    int g = tid >> 2, s = tid & 3;               // Q-build: 4 threads/dst, 32 feats each
    int wave = tid >> 6, lane = tid & 63;
    int nl = lane & 15, q = lane >> 4;

    f32x4 acc[4][2];
    #pragma unroll
    for (int m = 0; m < 4; ++m) {
        acc[m][0] = (f32x4){0.f, 0.f, 0.f, 0.f};
        acc[m][1] = (f32x4){0.f, 0.f, 0.f, 0.f};
    }

    // ---- build rel 0 into Qt[0] ----
    {
        int key = v0 + g;                        // r=0
        int beg = offs[key], end = offs[key + 1];
        float qa[32];
        #pragma unroll
        for (int i = 0; i < 32; ++i) qa[i] = 0.f;
        for (int e = beg; e < end; ++e) {
            const uint4* xr = (const uint4*)(x + srcs[e] * 128 + s * 32);
            uint4 p[4] = {xr[0], xr[1], xr[2], xr[3]};
            accum32(qa, p);
        }
        pack32(qa, &Qt[g * QT_STRIDE + s * 32]);
    }
    __syncthreads();

    for (int r = 0; r < 17; ++r) {
        int buf = r & 1;
        // ---- B fragments for rel r (global, L2-resident) ----
        bf16x8 Bf[2][4];
        {
            const unsigned short* wr = Wb + r * 16384;
            #pragma unroll
            for (int nt = 0; nt < 2; ++nt) {
                int n = wave * 32 + nt * 16 + nl;
                #pragma unroll
                for (int kc = 0; kc < 4; ++kc)
                    Bf[nt][kc] = *(const bf16x8*)(wr + n * 128 + kc * 32 + q * 8);
            }
        }
        // ---- prefetch gathers for rel r+1 (land during MFMA) ----
        int r1 = r + 1;
        int beg = 0, end = 0;
        if (r1 < 16) { int key = r1 * N_PAD + (v0 + g); beg = offs[key]; end = offs[key + 1]; }
        else if (r1 == 16) { beg = 0; end = 1; }
        bool h0 = end > beg, h1 = end > beg + 1;
        uint4 p0[4], p1[4];
        if (r1 <= 16) {
            if (h0) {
                int s0 = (r1 == 16) ? (v0 + g) : srcs[beg];
                const uint4* xr = (const uint4*)(x + s0 * 128 + s * 32);
                p0[0] = xr[0]; p0[1] = xr[1]; p0[2] = xr[2]; p0[3] = xr[3];
            }
            if (h1) {
                int s1i = srcs[beg + 1];
                const uint4* xr = (const uint4*)(x + s1i * 128 + s * 32);
                p1[0] = xr[0]; p1[1] = xr[1]; p1[2] = xr[2]; p1[3] = xr[3];
            }
        }
        // ---- MFMA rel r from Qt[buf] ----
        {
            const unsigned short* qb = Qt + buf * QSZ;
            #pragma unroll
            for (int kc = 0; kc < 4; ++kc) {
                bf16x8 a[4];
                #pragma unroll
                for (int m = 0; m < 4; ++m)
                    a[m] = *(const bf16x8*)(qb + (m * 16 + nl) * QT_STRIDE + kc * 32 + q * 8);
                #pragma unroll
                for (int m = 0; m < 4; ++m) {
                    acc[m][0] = __builtin_amdgcn_mfma_f32_16x16x32_bf16(a[m], Bf[0][kc], acc[m][0], 0, 0, 0);
                    acc[m][1] = __builtin_amdgcn_mfma_f32_16x16x32_bf16(a[m], Bf[1][kc], acc[m][1], 0, 0, 0);
                }
            }
        }
        // ---- finish Q-build for rel r+1 into Qt[buf^1] ----
        if (r1 <= 16) {
            float qa[32];
            #pragma unroll
            for (int i = 0; i < 32; ++i) qa[i] = 0.f;
            if (h0) accum32(qa, p0);
            if (h1) accum32(qa, p1);
            for (int e = beg + 2; e < end; ++e) {
                const uint4* xr = (const uint4*)(x + srcs[e] * 128 + s * 32);
                uint4 p[4] = {xr[0], xr[1], xr[2], xr[3]};
                accum32(qa, p);
            }
            pack32(qa, &Qt[(buf ^ 1) * QSZ + g * QT_STRIDE + s * 32]);
        }
        __syncthreads();
    }

    // ---- epilogue: C layout col=lane&15, row=q*4+reg ----
    #pragma unroll
    for (int m = 0; m < 4; ++m) {
        #pragma unroll
        for (int nt = 0; nt < 2; ++nt) {
            int col = wave * 32 + nt * 16 + nl;
            float bv = bias[col];
            #pragma unroll
            for (int reg = 0; reg < 4; ++reg) {
                int node = v0 + m * 16 + q * 4 + reg;
                float val = acc[m][nt][reg] + bv;
                if (out_bf16) out_bf16[node * 128 + col] = f2bf(fmaxf(val, 0.f));
                else          out_f32[node * 128 + col]  = val;
            }
        }
    }
}

__global__ void k_pool(const float* __restrict__ agg2, const int* __restrict__ gids,
                       float* __restrict__ hg_sum, int* __restrict__ cnt)
{
    int d  = threadIdx.x;                    // 128
    int n0 = blockIdx.x * POOL_CH;
    int nend = min(n0 + POOL_CH, N_NODES);
    int curg = gids[n0];
    float run = 0.f;
    for (int n = n0; n < nend; ++n) {
        int g = gids[n];
        if (g != curg) { atomAddF(&hg_sum[curg*DIM + d], run); run = 0.f; curg = g; }
        run += fmaxf(agg2[n*DIM + d], 0.f);
    }
    atomAddF(&hg_sum[curg*DIM + d], run);
    if (d == 0) {
        int cg = gids[n0]; int rl = 0;
        for (int n = n0; n < nend; ++n) {
            int g = gids[n];
            if (g != cg) { atomicAdd(&cnt[cg], rl); rl = 0; cg = g; }
            rl++;
        }
        atomicAdd(&cnt[cg], rl);
    }
}

__global__ __launch_bounds__(256) void k_head(
    const float* __restrict__ hg_sum, const int* __restrict__ cnt,
    const float* __restrict__ Wfc, const float* __restrict__ bfc,
    const float* __restrict__ Wc, const float* __restrict__ bc,
    float* __restrict__ out)
{
    int g = blockIdx.x, t = threadIdx.x;
    __shared__ float hgl[DIM];
    __shared__ float fcl[FC_DIM];
    __shared__ float lg[N_CLASSES];
    if (t < DIM) {
        float c = (float)max(cnt[g], 1);
        hgl[t] = hg_sum[g*DIM + t] / c;
    }
    __syncthreads();
    {
        float sv = bfc[t];
        #pragma unroll 4
        for (int k = 0; k < DIM; ++k) sv += hgl[k] * Wfc[k*FC_DIM + t];
        fcl[t] = fmaxf(sv, 0.f);
    }
    __syncthreads();
    if (t < N_CLASSES) {
        float l = bc[t];
        #pragma unroll 4
        for (int k = 0; k < FC_DIM; ++k) l += fcl[k] * Wc[k*N_CLASSES + t];
        lg[t] = l;
    }
    __syncthreads();
    if (t < N_CLASSES) {
        float m = lg[0];
        #pragma unroll
        for (int c = 1; c < N_CLASSES; ++c) m = fmaxf(m, lg[c]);
        float sden = 0.f;
        #pragma unroll
        for (int c = 0; c < N_CLASSES; ++c) sden += expf(lg[c] - m);
        out[g*N_CLASSES + t] = expf(lg[t] - m) / sden;
    }
}

extern "C" void kernel_launch(void* const* d_in, const int* in_sizes, int n_in,
                              void* d_out, int out_size, void* d_ws, size_t ws_size,
                              hipStream_t stream)
{
    const float* h   = (const float*)d_in[0];
    const int*   src = (const int*)d_in[1];
    const int*   dst = (const int*)d_in[2];
    const int*   rel = (const int*)d_in[3];
    const int*   gid = (const int*)d_in[4];
    const float* W1  = (const float*)d_in[5];
    const float* Ws1 = (const float*)d_in[6];
    const float* b1  = (const float*)d_in[7];
    const float* W2  = (const float*)d_in[8];
    const float* Ws2 = (const float*)d_in[9];
    const float* b2  = (const float*)d_in[10];
    const float* Wfc = (const float*)d_in[11];
    const float* bfc = (const float*)d_in[12];
    const float* Wc  = (const float*)d_in[13];
    const float* bc  = (const float*)d_in[14];
    float* out = (float*)d_out;

    char* ws = (char*)d_ws;
    int*   hist  = (int*)(ws + WS_HIST);
    float* hgsum = (float*)(ws + WS_HG);
    int*   cnt   = (int*)(ws + WS_CNT);
    int*   offs  = (int*)(ws + WS_OFFS);
    int*   cur   = (int*)(ws + WS_CUR);
    int*   part  = (int*)(ws + WS_PART);
    int*   srcs  = (int*)(ws + WS_SRCS);
    unsigned short* x1  = (unsigned short*)(ws + WS_X1);
    unsigned short* x2  = (unsigned short*)(ws + WS_X2);
    float* agg2  = (float*)(ws + WS_AGG2);
    unsigned short* Wb1 = (unsigned short*)(ws + WS_WB);
    unsigned short* Wb2 = Wb1 + 17 * 16384;

    hipMemsetAsync(hist, 0, MEMSET_SZ, stream);   // hist + hgsum + cnt contiguous

    k_convX<<<(N_PAD * DIM) / 256, 256, 0, stream>>>(h, x1);
    k_convW<<<(2 * 17 * 16384) / 256, 256, 0, stream>>>(W1, Ws1, W2, Ws2, Wb1);

    k_histK<<<(N_EDGES + 255) / 256, 256, 0, stream>>>(dst, rel, hist);
    k_scanA<<<NBLK_SCAN, 256, 0, stream>>>(hist, part);
    k_scanB<<<1, 256, 0, stream>>>(part, offs + NBINS);
    k_scanC<<<NBLK_SCAN, 256, 0, stream>>>(hist, part, offs, cur);
    k_scatterK<<<(N_EDGES + 255) / 256, 256, 0, stream>>>(src, dst, rel, cur, srcs);

    k_layer<<<NTILES, 256, 0, stream>>>(x1, Wb1, offs, srcs, b1, x2, nullptr);
    k_layer<<<NTILES, 256, 0, stream>>>(x2, Wb2, offs, srcs, b2, nullptr, agg2);

    k_pool<<<(N_NODES + POOL_CH - 1) / POOL_CH, 128, 0, stream>>>(agg2, gid, hgsum, cnt);
    k_head<<<N_GRAPHS, 256, 0, stream>>>(hgsum, cnt, Wfc, bfc, Wc, bc, out);
}